// Round 3
// baseline (384.012 us; speedup 1.0000x reference)
//
#include <hip/hip_runtime.h>
#include <math.h>

// Problem constants: x [16,64,256,256] f32, mask [16,256,256] i32
#define BATCH 16
#define CH    64
#define HW    65536          // 256*256
#define HW4   16384          // HW/4 (float4 units)
#define NBLKP 1024           // pool: 64 blocks/batch * 16 batches (128-thr, P=2)

#define RED4(acc_max, acc_min, acc_sum, t)                                        \
    (acc_max).x = fmaxf((acc_max).x, (t).x); (acc_max).y = fmaxf((acc_max).y, (t).y); \
    (acc_max).z = fmaxf((acc_max).z, (t).z); (acc_max).w = fmaxf((acc_max).w, (t).w); \
    (acc_min).x = fminf((acc_min).x, (t).x); (acc_min).y = fminf((acc_min).y, (t).y); \
    (acc_min).z = fminf((acc_min).z, (t).z); (acc_min).w = fminf((acc_min).w, (t).w); \
    (acc_sum).x += (t).x; (acc_sum).y += (t).y; (acc_sum).z += (t).z; (acc_sum).w += (t).w;

#define STAT1(mkc, mx, mn, me)                       \
    if ((mkc) == 1) { vals[0] += 1.f;                \
        vals[1] += (mx); vals[4] += (mx) * (mx);     \
        vals[2] += (me); vals[5] += (me) * (me);     \
        vals[3] += (mn); vals[6] += (mn) * (mn); }

// P=2 pixels/thread, second pixel offset by one wave-width (64 float4s):
// each wave's per-channel visit issues two ADDRESS-ADJACENT 1 KB loads
// (2 KB contiguous DRAM granule vs 1 KB before). 1024 blocks = 4 blocks/CU
// x 2 waves = 8 waves/CU; 8 loads in flight/thread = 64 KB/CU outstanding
// (Little's law needs ~9 KB at 24.6 GB/s/CU, 900cy latency -> covered).
__global__ __launch_bounds__(128, 4) void pool_stats_kernel(
    const float* __restrict__ x, const int* __restrict__ mask,
    float* __restrict__ out, float* __restrict__ part)
{
    const int b    = blockIdx.x >> 6;           // batch (64 blocks/batch)
    const int pblk = blockIdx.x & 63;           // pixel-block within batch
    const int lane = threadIdx.x & 63;
    const int wid  = threadIdx.x >> 6;
    const int i0   = pblk * 256 + wid * 128 + lane;   // 1st float4; 2nd = i0+64

    const float4* xb = (const float4*)x + (size_t)b * CH * HW4 + i0;

    // mask loads first; latency hides under the x stream
    const int4 mk0 = ((const int4*)mask)[(size_t)b * HW4 + i0];
    const int4 mk1 = ((const int4*)mask)[(size_t)b * HW4 + i0 + 64];

    float4 max0 = make_float4(-INFINITY, -INFINITY, -INFINITY, -INFINITY);
    float4 max1 = max0;
    float4 min0 = make_float4( INFINITY,  INFINITY,  INFINITY,  INFINITY);
    float4 min1 = min0;
    float4 sum0 = make_float4(0.f, 0.f, 0.f, 0.f);
    float4 sum1 = sum0;

    // 4 channels x 2 pixels in flight = 8 float4 loads (32 VGPR buffer).
    for (int c0 = 0; c0 < CH; c0 += 4) {
        float4 t[4][2];
#pragma unroll
        for (int j = 0; j < 4; ++j) {
            const float4* p = xb + (size_t)(c0 + j) * HW4;
            t[j][0] = p[0];
            t[j][1] = p[64];
        }
#pragma unroll
        for (int j = 0; j < 4; ++j) {
            RED4(max0, min0, sum0, t[j][0]);
            RED4(max1, min1, sum1, t[j][1]);
        }
    }

    const float inv = 1.0f / 64.0f;
    float4 mean0 = make_float4(sum0.x * inv, sum0.y * inv, sum0.z * inv, sum0.w * inv);
    float4 mean1 = make_float4(sum1.x * inv, sum1.y * inv, sum1.z * inv, sum1.w * inv);

    // write pooled channels [max, mean, min] into d_out [B,3,H,W]
    float4* ob = (float4*)out + (size_t)b * 3 * HW4 + i0;
    ob[0]           = max0;  ob[64]           = max1;
    ob[HW4]         = mean0; ob[HW4 + 64]     = mean1;
    ob[2 * HW4]     = min0;  ob[2 * HW4 + 64] = min1;

    // masked partial sums for this thread's 8 pixels (both groups, same batch)
    float vals[7] = {0.f, 0.f, 0.f, 0.f, 0.f, 0.f, 0.f}; // cnt, S1[3], S2[3]
    STAT1(mk0.x, max0.x, min0.x, mean0.x)
    STAT1(mk0.y, max0.y, min0.y, mean0.y)
    STAT1(mk0.z, max0.z, min0.z, mean0.z)
    STAT1(mk0.w, max0.w, min0.w, mean0.w)
    STAT1(mk1.x, max1.x, min1.x, mean1.x)
    STAT1(mk1.y, max1.y, min1.y, mean1.y)
    STAT1(mk1.z, max1.z, min1.z, mean1.z)
    STAT1(mk1.w, max1.w, min1.w, mean1.w)

    // wave (64-lane) shuffle reduction
    for (int off = 32; off > 0; off >>= 1) {
#pragma unroll
        for (int k = 0; k < 7; ++k)
            vals[k] += __shfl_down(vals[k], off, 64);
    }

    // cross-wave (2 waves) LDS reduction -> one contention-free slot per block
    __shared__ float red[2][8];
    if (lane == 0) {
#pragma unroll
        for (int k = 0; k < 7; ++k) red[wid][k] = vals[k];
    }
    __syncthreads();
    if (threadIdx.x < 7) {
        const int k = threadIdx.x;
        part[blockIdx.x * 8 + k] = red[0][k] + red[1][k];
    }
}

// One block per 256 float4s of out; folds stats finalization (redundant
// per-block reduce of batch b's 64 partial slots, ~2 KB from L2) + normalize.
__global__ __launch_bounds__(256) void norm_kernel(
    float* __restrict__ out, const int* __restrict__ mask,
    const float* __restrict__ part)
{
    const int i4   = blockIdx.x * 256 + threadIdx.x;   // [0, 3*B*HW4)
    const int bc   = i4 >> 14;                         // (b*3 + c)
    const int idx4 = i4 & (HW4 - 1);
    const int b    = bc / 3;

    // redundant stats reduce: batch b's 64 partial slots (1 per lane)
    __shared__ float sstat[6];   // mean[3], rstd[3]
    if (threadIdx.x < 64) {
        const float* pb = part + (size_t)(b * 64 + threadIdx.x) * 8;
        float s[7];
#pragma unroll
        for (int k = 0; k < 7; ++k) s[k] = pb[k];
        for (int off = 32; off > 0; off >>= 1) {
#pragma unroll
            for (int k = 0; k < 7; ++k)
                s[k] += __shfl_down(s[k], off, 64);
        }
        if (threadIdx.x == 0) {
            const float cnt = s[0];
#pragma unroll
            for (int c = 0; c < 3; ++c) {
                const float S1 = s[1 + c];
                const float S2 = s[4 + c];
                sstat[c]     = S1 / cnt;
                sstat[3 + c] = 1.0f / sqrtf((S2 - S1 * S1 / cnt) / (cnt - 1.0f));
            }
        }
    }
    __syncthreads();

    const int   c    = bc - b * 3;
    const float mean = sstat[c];
    const float rstd = sstat[3 + c];

    float4 v = ((const float4*)out)[i4];
    int4 mk  = ((const int4*)mask)[(size_t)b * HW4 + idx4];
    v.x = (mk.x == 1) ? (v.x - mean) * rstd : 0.0f;
    v.y = (mk.y == 1) ? (v.y - mean) * rstd : 0.0f;
    v.z = (mk.z == 1) ? (v.z - mean) * rstd : 0.0f;
    v.w = (mk.w == 1) ? (v.w - mean) * rstd : 0.0f;
    ((float4*)out)[i4] = v;
}

extern "C" void kernel_launch(void* const* d_in, const int* in_sizes, int n_in,
                              void* d_out, int out_size, void* d_ws, size_t ws_size,
                              hipStream_t stream)
{
    const float* x    = (const float*)d_in[0];
    const int*   mask = (const int*)d_in[1];
    float*       out  = (float*)d_out;
    float*       part = (float*)d_ws;   // 1024 * 8 floats = 32 KB

    pool_stats_kernel<<<NBLKP, 128, 0, stream>>>(x, mask, out, part);
    norm_kernel<<<3 * BATCH * HW4 / 256, 256, 0, stream>>>(out, mask, part);
}